// Round 11
// baseline (92.705 us; speedup 1.0000x reference)
//
#include <hip/hip_runtime.h>

#define KS    13
#define HALF  6
#define TY    32              // output rows per strip
#define NITER (TY + 12)       // 44 bodies: 12 prologue (fill window) + TY output rows
#define IMG_H 1024
#define IMG_W 1024

__device__ __forceinline__ int reflect_idx(int i, int n) {
    if (i < 0) i = -i;
    if (i >= n) i = 2 * n - 2 - i;
    return i;
}

struct Ctx {
    const float* xin;
    float*       o;
    float        g[KS];
    int          t;        // thread's column granule: output cols 4t..4t+3
    int          r0;       // strip's first output row
    bool         interior; // 2 <= t <= 253 : H-window needs no column reflect
};

// Body n (= outer*13 + U): reads raw input row (r0+n-6) H-window straight from
// global (5 coalesced float4 loads -- all lanes same row, consecutive granules;
// overlapping loads hit L1/L2, input is L3-resident), H-filters into window slot
// U%13, then (n>=12) V-filters the window -> output row r0+n-12.
// No LDS, no barriers: waves free-run. Window indices compile-time (rule #20).
template<int U>
__device__ __forceinline__ void body(int outer, const Ctx& cx, float4 (&w)[KS])
{
    const int n = outer * 13 + U;
    if (n >= NITER) return;

    const int rr = reflect_idx(cx.r0 + n - 6, IMG_H);
    const float* rp = cx.xin + (size_t)rr * IMG_W;

    // 20-float horizontal window (floats 4t-8 .. 4t+11); f[2..17] are used
    float f[20];
    if (cx.interior) {
        #pragma unroll
        for (int k = 0; k < 5; ++k) {
            float4 v = *reinterpret_cast<const float4*>(rp + 4 * cx.t - 8 + 4 * k);
            f[4*k+0] = v.x; f[4*k+1] = v.y; f[4*k+2] = v.z; f[4*k+3] = v.w;
        }
    } else {
        #pragma unroll
        for (int k = 0; k < 20; ++k)
            f[k] = rp[reflect_idx(4 * cx.t - 8 + k, IMG_W)];
    }

    // H: 13 taps x 4 columns
    float4 h = make_float4(0.f, 0.f, 0.f, 0.f);
    #pragma unroll
    for (int j = 0; j < KS; ++j) {
        h.x += cx.g[j] * f[2 + j];
        h.y += cx.g[j] * f[3 + j];
        h.z += cx.g[j] * f[4 + j];
        h.w += cx.g[j] * f[5 + j];
    }
    w[U % KS] = h;

    // V: 13 taps over the rolling register window -> output row r0 + n - 12
    if (n >= 12) {
        float4 a = make_float4(0.f, 0.f, 0.f, 0.f);
        #pragma unroll
        for (int j = 0; j < KS; ++j) {
            const float4 v = w[(U + 1 + j) % KS];
            a.x += cx.g[j] * v.x;
            a.y += cx.g[j] * v.y;
            a.z += cx.g[j] * v.z;
            a.w += cx.g[j] * v.w;
        }
        *reinterpret_cast<float4*>(cx.o + (size_t)(cx.r0 + n - 12) * IMG_W + 4 * cx.t) = a;
    }
}

// No launch-bounds min-waves (R2: VGPR cap -> spill). Expect ~105 VGPR (<=128
// keeps 4 waves/SIMD). No LDS at all.
__global__ __launch_bounds__(256) void gauss_blur_stream(
    const float* __restrict__ x, const float* __restrict__ k2d,
    float* __restrict__ out)
{
    Ctx cx;
    cx.t  = threadIdx.x;
    cx.r0 = blockIdx.x * TY;
    const int img = blockIdx.y;
    cx.xin = x + (size_t)img * IMG_H * IMG_W;
    cx.o   = out + (size_t)img * IMG_H * IMG_W;
    cx.interior = (cx.t >= 2) && (cx.t <= 253);

    // 1D taps: k2d = outer(g,g) exactly, g[i] = k2d[i][6]/sqrt(k2d[6][6])
    {
        float c   = k2d[HALF * KS + HALF];
        float inv = 1.0f / sqrtf(c);
        #pragma unroll
        for (int j = 0; j < KS; ++j) cx.g[j] = k2d[j * KS + HALF] * inv;
    }

    float4 w[KS];
    for (int outer = 0; outer < (NITER + 12) / 13; ++outer) {
        body< 0>(outer, cx, w);
        body< 1>(outer, cx, w);
        body< 2>(outer, cx, w);
        body< 3>(outer, cx, w);
        body< 4>(outer, cx, w);
        body< 5>(outer, cx, w);
        body< 6>(outer, cx, w);
        body< 7>(outer, cx, w);
        body< 8>(outer, cx, w);
        body< 9>(outer, cx, w);
        body<10>(outer, cx, w);
        body<11>(outer, cx, w);
        body<12>(outer, cx, w);
    }
}

extern "C" void kernel_launch(void* const* d_in, const int* in_sizes, int n_in,
                              void* d_out, int out_size, void* d_ws, size_t ws_size,
                              hipStream_t stream) {
    const float* x   = (const float*)d_in[0];
    const float* k2d = (const float*)d_in[1];
    float*       out = (float*)d_out;

    dim3 grid(IMG_H / TY, 32);   // 32 strips x 32 images = 1024 blocks (4/CU, 16 waves)
    gauss_blur_stream<<<grid, 256, 0, stream>>>(x, k2d, out);
}

// Round 12
// 74.479 us; speedup vs baseline: 1.2447x; 1.2447x over previous
//
#include <hip/hip_runtime.h>

#define KS    13
#define HALF  6
#define TY    16              // output rows per strip (16 -> 2048 blocks, 6 resident/CU)
#define NITER (TY + 12)       // 28 bodies: 12 prologue (fill window) + TY output rows
#define IMG_H 1024
#define IMG_W 1024

__device__ __forceinline__ int reflect_idx(int i, int n) {
    if (i < 0) i = -i;
    if (i >= n) i = 2 * n - 2 - i;
    return i;
}

struct Ctx {
    const float* xin;
    float*       o;
    float        g[KS];
    int          t;        // thread's column granule: cols 4t..4t+3
    int          r0;       // strip's first output row
    bool         interior; // 2 <= t <= 253 : LDS window read needs no column reflect
};

// Body n (= outer*13 + U): commits raw input row (r0+n-6) to LDS, H-filters it into
// window slot U, then (n>=12) V-filters the window -> output row r0+n-12.
// All window indices are compile-time constants (U literal) -> registers, no scratch.
template<int U>
__device__ __forceinline__ void body(int outer, const Ctx& cx, float (*s)[IMG_W],
                                     float4 (&w)[KS], float4& cur)
{
    const int n = outer * 13 + U;
    if (n >= NITER) return;                 // block-uniform guard (barrier-safe)
    const int buf = n & 1;

    // issue next raw-row load early: in flight under H+V compute (T14, 8 VGPR)
    float4 nxt = cur;
    if (n + 1 < NITER) {
        const int rr = reflect_idx(cx.r0 + n - 5, IMG_H);
        nxt = *reinterpret_cast<const float4*>(cx.xin + (size_t)rr * IMG_W + 4 * cx.t);
    }

    // commit current raw row to ping-pong LDS; ONE barrier/row is WAR-safe:
    // body n+2 re-writes s[buf] only after barrier n+1, which follows body n's reads.
    *reinterpret_cast<float4*>(&s[buf][4 * cx.t]) = cur;
    __syncthreads();

    // 20-float horizontal window (granules 4t-8 .. 4t+8); edge threads reflect
    float f[20];
    if (cx.interior) {
        #pragma unroll
        for (int k = 0; k < 5; ++k) {
            float4 v = *reinterpret_cast<const float4*>(&s[buf][4 * cx.t - 8 + 4 * k]);
            f[4*k+0] = v.x; f[4*k+1] = v.y; f[4*k+2] = v.z; f[4*k+3] = v.w;
        }
    } else {
        #pragma unroll
        for (int k = 0; k < 20; ++k)
            f[k] = s[buf][reflect_idx(4 * cx.t - 8 + k, IMG_W)];
    }

    // H: 13 taps x 4 columns
    float4 h = make_float4(0.f, 0.f, 0.f, 0.f);
    #pragma unroll
    for (int j = 0; j < KS; ++j) {
        h.x += cx.g[j] * f[2 + j];
        h.y += cx.g[j] * f[3 + j];
        h.z += cx.g[j] * f[4 + j];
        h.w += cx.g[j] * f[5 + j];
    }
    w[U % KS] = h;

    // V: 13 taps over the rolling window -> output row r0 + n - 12
    if (n >= 12) {
        float4 a = make_float4(0.f, 0.f, 0.f, 0.f);
        #pragma unroll
        for (int j = 0; j < KS; ++j) {
            const float4 v = w[(U + 1 + j) % KS];
            a.x += cx.g[j] * v.x;
            a.y += cx.g[j] * v.y;
            a.z += cx.g[j] * v.z;
            a.w += cx.g[j] * v.w;
        }
        *reinterpret_cast<float4*>(cx.o + (size_t)(cx.r0 + n - 12) * IMG_W + 4 * cx.t) = a;
    }
    cur = nxt;
}

// No launch-bounds min-waves (R2: VGPR cap -> spill). ~80 VGPR -> 6 blocks/CU.
__global__ __launch_bounds__(256) void gauss_blur_stream(
    const float* __restrict__ x, const float* __restrict__ k2d,
    float* __restrict__ out)
{
    __shared__ float s[2][IMG_W];   // 8192 B ping-pong raw-row buffer

    Ctx cx;
    cx.t  = threadIdx.x;
    cx.r0 = blockIdx.x * TY;
    const int img = blockIdx.y;
    cx.xin = x + (size_t)img * IMG_H * IMG_W;
    cx.o   = out + (size_t)img * IMG_H * IMG_W;
    cx.interior = (cx.t >= 2) && (cx.t <= 253);

    // 1D taps: k2d = outer(g,g) exactly, g[i] = k2d[i][6]/sqrt(k2d[6][6])
    {
        float c   = k2d[HALF * KS + HALF];
        float inv = 1.0f / sqrtf(c);
        #pragma unroll
        for (int j = 0; j < KS; ++j) cx.g[j] = k2d[j * KS + HALF] * inv;
    }

    float4 w[KS];
    // preload raw row for body 0: input row r0 - 6 (reflected)
    float4 cur = *reinterpret_cast<const float4*>(
        cx.xin + (size_t)reflect_idx(cx.r0 - 6, IMG_H) * IMG_W + 4 * cx.t);

    for (int outer = 0; outer < (NITER + 12) / 13; ++outer) {
        body< 0>(outer, cx, s, w, cur);
        body< 1>(outer, cx, s, w, cur);
        body< 2>(outer, cx, s, w, cur);
        body< 3>(outer, cx, s, w, cur);
        body< 4>(outer, cx, s, w, cur);
        body< 5>(outer, cx, s, w, cur);
        body< 6>(outer, cx, s, w, cur);
        body< 7>(outer, cx, s, w, cur);
        body< 8>(outer, cx, s, w, cur);
        body< 9>(outer, cx, s, w, cur);
        body<10>(outer, cx, s, w, cur);
        body<11>(outer, cx, s, w, cur);
        body<12>(outer, cx, s, w, cur);
    }
}

extern "C" void kernel_launch(void* const* d_in, const int* in_sizes, int n_in,
                              void* d_out, int out_size, void* d_ws, size_t ws_size,
                              hipStream_t stream) {
    const float* x   = (const float*)d_in[0];
    const float* k2d = (const float*)d_in[1];
    float*       out = (float*)d_out;

    dim3 grid(IMG_H / TY, 32);   // 64 strips x 32 images = 2048 blocks
    gauss_blur_stream<<<grid, 256, 0, stream>>>(x, k2d, out);
}

// Round 13
// 54.455 us; speedup vs baseline: 1.7024x; 1.3677x over previous
//
#include <hip/hip_runtime.h>

#define KS    13
#define HALF  6
#define TY    32              // output rows per strip (R10 geometry — best measured)
#define NITER (TY + 12)       // 44 staged rows
#define NK    (NITER / 2)     // 22 iterations, 2 rows per barrier
#define IMG_H 1024
#define IMG_W 1024

__device__ __forceinline__ int reflect_idx(int i, int n) {
    if (i < 0) i = -i;
    if (i >= n) i = 2 * n - 2 - i;
    return i;
}

struct Ctx {
    const float* xin;
    float*       o;
    float        g[KS];
    int          t;        // thread's column granule: cols 4t..4t+3
    int          r0;       // strip's first output row
    bool         interior; // 2 <= t <= 253 : LDS window read needs no column reflect
};

// H-filter one staged row from LDS: 20-float window -> 4 outputs.
__device__ __forceinline__ float4 h_filter(const float* srow, const Ctx& cx) {
    float f[20];
    if (cx.interior) {
        #pragma unroll
        for (int k = 0; k < 5; ++k) {
            float4 v = *reinterpret_cast<const float4*>(srow + 4 * cx.t - 8 + 4 * k);
            f[4*k+0] = v.x; f[4*k+1] = v.y; f[4*k+2] = v.z; f[4*k+3] = v.w;
        }
    } else {
        #pragma unroll
        for (int k = 0; k < 20; ++k)
            f[k] = srow[reflect_idx(4 * cx.t - 8 + k, IMG_W)];
    }
    float4 h = make_float4(0.f, 0.f, 0.f, 0.f);
    #pragma unroll
    for (int j = 0; j < KS; ++j) {
        h.x += cx.g[j] * f[2 + j];
        h.y += cx.g[j] * f[3 + j];
        h.z += cx.g[j] * f[4 + j];
        h.w += cx.g[j] * f[5 + j];
    }
    return h;
}

// Iteration k (= outer*7 + U): stages raw rows n0=2k, n1=2k+1 (input rows r0+n-6)
// into the (k&1) LDS pair, ONE barrier, H-filters both into window slots
// (2U)%14,(2U+1)%14, then (k>=6) V-filters -> output rows r0+2k-12, r0+2k-11.
// All window indices compile-time (template U) -> registers, no scratch (rule #20).
// WAR safety: iter k's reads precede its bar_{k+1}; iter k+2's rewrites of this
// pair follow bar_{k+1} (same proof as the 1-row ping-pong).
template<int U>
__device__ __forceinline__ void body2(int outer, const Ctx& cx, float (*s)[IMG_W],
                                      float4 (&w)[14], float4& cur0, float4& cur1)
{
    const int k = outer * 7 + U;
    if (k >= NK) return;                 // block-uniform guard (barrier-safe)
    const int n0 = 2 * k;
    const int bp = (k & 1) * 2;          // LDS buffer pair

    // commit staged rows; then issue next pair's loads (in flight across barrier+compute)
    *reinterpret_cast<float4*>(&s[bp + 0][4 * cx.t]) = cur0;
    *reinterpret_cast<float4*>(&s[bp + 1][4 * cx.t]) = cur1;
    if (k + 1 < NK) {
        const int ra = reflect_idx(cx.r0 + n0 - 4, IMG_H);  // row n0+2
        const int rb = reflect_idx(cx.r0 + n0 - 3, IMG_H);  // row n0+3
        cur0 = *reinterpret_cast<const float4*>(cx.xin + (size_t)ra * IMG_W + 4 * cx.t);
        cur1 = *reinterpret_cast<const float4*>(cx.xin + (size_t)rb * IMG_W + 4 * cx.t);
    }
    __syncthreads();

    // two H-filters into the rolling 14-slot window
    w[(2 * U) % 14]     = h_filter(s[bp + 0], cx);
    w[(2 * U + 1) % 14] = h_filter(s[bp + 1], cx);

    // two V-filters -> output rows r0+n0-12, r0+n0-11
    if (n0 >= 12) {
        float4 a0 = make_float4(0.f, 0.f, 0.f, 0.f);
        float4 a1 = make_float4(0.f, 0.f, 0.f, 0.f);
        #pragma unroll
        for (int j = 0; j < KS; ++j) {
            const float4 v0 = w[(2 * U + 2 + j) % 14];
            const float4 v1 = w[(2 * U + 3 + j) % 14];
            a0.x += cx.g[j] * v0.x;  a1.x += cx.g[j] * v1.x;
            a0.y += cx.g[j] * v0.y;  a1.y += cx.g[j] * v1.y;
            a0.z += cx.g[j] * v0.z;  a1.z += cx.g[j] * v1.z;
            a0.w += cx.g[j] * v0.w;  a1.w += cx.g[j] * v1.w;
        }
        *reinterpret_cast<float4*>(cx.o + (size_t)(cx.r0 + n0 - 12) * IMG_W + 4 * cx.t) = a0;
        *reinterpret_cast<float4*>(cx.o + (size_t)(cx.r0 + n0 - 11) * IMG_W + 4 * cx.t) = a1;
    }
}

// No launch-bounds min-waves (R2: VGPR cap -> spill). Expect ~110 VGPR.
__global__ __launch_bounds__(256) void gauss_blur_stream(
    const float* __restrict__ x, const float* __restrict__ k2d,
    float* __restrict__ out)
{
    __shared__ float s[4][IMG_W];   // 16384 B: two ping-pong row PAIRS

    Ctx cx;
    cx.t  = threadIdx.x;
    cx.r0 = blockIdx.x * TY;
    const int img = blockIdx.y;
    cx.xin = x + (size_t)img * IMG_H * IMG_W;
    cx.o   = out + (size_t)img * IMG_H * IMG_W;
    cx.interior = (cx.t >= 2) && (cx.t <= 253);

    // 1D taps: k2d = outer(g,g) exactly, g[i] = k2d[i][6]/sqrt(k2d[6][6])
    {
        float c   = k2d[HALF * KS + HALF];
        float inv = 1.0f / sqrtf(c);
        #pragma unroll
        for (int j = 0; j < KS; ++j) cx.g[j] = k2d[j * KS + HALF] * inv;
    }

    float4 w[14];
    // preload rows n=0,1 (input rows r0-6, r0-5, reflected)
    float4 cur0 = *reinterpret_cast<const float4*>(
        cx.xin + (size_t)reflect_idx(cx.r0 - 6, IMG_H) * IMG_W + 4 * cx.t);
    float4 cur1 = *reinterpret_cast<const float4*>(
        cx.xin + (size_t)reflect_idx(cx.r0 - 5, IMG_H) * IMG_W + 4 * cx.t);

    for (int outer = 0; outer < 4; ++outer) {   // 4*7 = 28 bodies, guard k<22
        body2<0>(outer, cx, s, w, cur0, cur1);
        body2<1>(outer, cx, s, w, cur0, cur1);
        body2<2>(outer, cx, s, w, cur0, cur1);
        body2<3>(outer, cx, s, w, cur0, cur1);
        body2<4>(outer, cx, s, w, cur0, cur1);
        body2<5>(outer, cx, s, w, cur0, cur1);
        body2<6>(outer, cx, s, w, cur0, cur1);
    }
}

extern "C" void kernel_launch(void* const* d_in, const int* in_sizes, int n_in,
                              void* d_out, int out_size, void* d_ws, size_t ws_size,
                              hipStream_t stream) {
    const float* x   = (const float*)d_in[0];
    const float* k2d = (const float*)d_in[1];
    float*       out = (float*)d_out;

    dim3 grid(IMG_H / TY, 32);   // 32 strips x 32 images = 1024 blocks
    gauss_blur_stream<<<grid, 256, 0, stream>>>(x, k2d, out);
}